// Round 17
// baseline (138.600 us; speedup 1.0000x reference)
//
#include <hip/hip_runtime.h>

#define F_IN 128
#define HID 64
#define NCLS 40

#define TSH 7              // tile shift
#define TS  128            // nodes per dst tile
#define NBMAX 800          // max tiles (N <= 102400)
#define GH 800             // ghist stride
#define NW 256             // writer blocks for hist/part

typedef __attribute__((ext_vector_type(8))) short bf16x8;
typedef __attribute__((ext_vector_type(4))) float f32x4;
typedef __attribute__((ext_vector_type(2))) float f32x2;
typedef __attribute__((ext_vector_type(4))) int int4v;
typedef __attribute__((ext_vector_type(2))) int int2v;

__device__ __forceinline__ unsigned short f2b(float f) {
    union { float f; unsigned int u; } v; v.f = f;
    unsigned int u = v.u + 0x7FFFu + ((v.u >> 16) & 1u);
    return (unsigned short)(u >> 16);
}
__device__ __forceinline__ float b2f(unsigned short b) {
    union { unsigned int u; float f; } v; v.u = ((unsigned int)b) << 16;
    return v.f;
}

// ---------------- K1: per-block histogram over dst tiles (int4 loads) ----------------
__global__ __launch_bounds__(256) void hist_kernel(
    const int* __restrict__ dst, int* __restrict__ ghist, int E, int NB)
{
    __shared__ int h[NBMAX];
    const int tid = threadIdx.x;
    for (int i = tid; i < NBMAX; i += 256) h[i] = 0;
    __syncthreads();
    int chunk = (E + NW - 1) / NW;
    chunk = (chunk + 3) & ~3;
    const int lo = blockIdx.x * chunk;
    const int hi = min(E, lo + chunk);
    for (int e = lo + tid * 4; e + 3 < hi; e += 1024) {
        int4v d4 = *(const int4v*)(dst + e);
        atomicAdd(&h[d4.x >> TSH], 1);
        atomicAdd(&h[d4.y >> TSH], 1);
        atomicAdd(&h[d4.z >> TSH], 1);
        atomicAdd(&h[d4.w >> TSH], 1);
    }
    {
        int tb = hi & ~3;
        if (tb < hi) {
            for (int e = tb + tid; e < hi; e += 256)
                atomicAdd(&h[dst[e] >> TSH], 1);
        }
    }
    __syncthreads();
    for (int bk = tid; bk < NB; bk += 256)
        ghist[blockIdx.x * GH + bk] = h[bk];
}

// ---------------- K2: tile totals ----------------
__global__ __launch_bounds__(256) void btot_kernel(
    const int* __restrict__ ghist, int* __restrict__ btot)
{
    __shared__ int s[256];
    const int bk = blockIdx.x, t = threadIdx.x;
    s[t] = ghist[t * GH + bk];
    __syncthreads();
    for (int off = 128; off > 0; off >>= 1) {
        if (t < off) s[t] += s[t + off];
        __syncthreads();
    }
    if (t == 0) btot[bk] = s[0];
}

// ---------------- K3: parallel exclusive scan of tile totals -> bbase ----------------
__global__ __launch_bounds__(256) void bscan_kernel(
    const int* __restrict__ btot, int* __restrict__ bbase, int NB)
{
    __shared__ int sls[256];
    const int t = threadIdx.x;
    const int base = t * 4;
    int a[4];
    #pragma unroll
    for (int k = 0; k < 4; k++) a[k] = (base + k < NB) ? btot[base + k] : 0;
    a[1] += a[0]; a[2] += a[1]; a[3] += a[2];
    sls[t] = a[3];
    __syncthreads();
    for (int off = 1; off < 256; off <<= 1) {
        int v = (t >= off) ? sls[t - off] : 0;
        __syncthreads();
        sls[t] += v;
        __syncthreads();
    }
    const int prefix = sls[t] - a[3];
    #pragma unroll
    for (int k = 0; k < 4; k++) {
        int excl = prefix + (k > 0 ? a[k - 1] : 0);
        if (base + k < NB) bbase[base + k] = excl;
    }
    if (t == 255) bbase[NB] = sls[255];
}

// ---------------- K4: per-(tile, block) offsets ----------------
__global__ __launch_bounds__(256) void boff_kernel(
    const int* __restrict__ ghist, const int* __restrict__ bbase,
    int* __restrict__ goff)
{
    __shared__ int s[256];
    const int bk = blockIdx.x, t = threadIdx.x;
    const int v = ghist[t * GH + bk];
    s[t] = v;
    __syncthreads();
    for (int off = 1; off < 256; off <<= 1) {
        int u = (t >= off) ? s[t - off] : 0;
        __syncthreads();
        s[t] += u;
        __syncthreads();
    }
    goff[bk * 256 + t] = bbase[bk] + s[t] - v;   // exclusive
}

// ---------------- K5: partition edges into tile-grouped staging (int4 loads) ----------------
__global__ __launch_bounds__(256) void part_kernel(
    const int* __restrict__ src, const int* __restrict__ dst,
    const int* __restrict__ goff, unsigned* __restrict__ staging, int E, int NB)
{
    __shared__ int cur[NBMAX];
    const int tid = threadIdx.x;
    const int blk = blockIdx.x;
    for (int bk = tid; bk < NB; bk += 256) cur[bk] = goff[bk * 256 + blk];
    __syncthreads();
    int chunk = (E + NW - 1) / NW;
    chunk = (chunk + 3) & ~3;
    const int lo = blk * chunk;
    const int hi = min(E, lo + chunk);
    for (int e = lo + tid * 4; e + 3 < hi; e += 1024) {
        int4v d4 = *(const int4v*)(dst + e);
        int4v s4 = *(const int4v*)(src + e);
        int d[4] = {d4.x, d4.y, d4.z, d4.w};
        int s[4] = {s4.x, s4.y, s4.z, s4.w};
        #pragma unroll
        for (int k = 0; k < 4; k++) {
            int bk = d[k] >> TSH;
            int p = atomicAdd(&cur[bk], 1);
            staging[p] = ((unsigned)(d[k] & (TS - 1)) << 17) | (unsigned)s[k];
        }
    }
    {
        int tb = hi & ~3;
        if (tb < hi) {
            for (int e = tb + tid; e < hi; e += 256) {
                int d = dst[e], s = src[e];
                int bk = d >> TSH;
                int p = atomicAdd(&cur[bk], 1);
                staging[p] = ((unsigned)(d & (TS - 1)) << 17) | (unsigned)s;
            }
        }
    }
}

// ---------------- K6: per-tile CSR build (rowptr slice + confined scatter) ----------------
__global__ __launch_bounds__(256) void build_kernel(
    const unsigned* __restrict__ staging, const int* __restrict__ bbase,
    int* __restrict__ rowptr, int* __restrict__ csr, int N)
{
    __shared__ int scnt[TS];
    __shared__ int sscan[TS];
    __shared__ int spos[TS];
    __shared__ int scur[TS];
    const int b = blockIdx.x, tid = threadIdx.x;
    if (tid < TS) { scnt[tid] = 0; scur[tid] = 0; }
    __syncthreads();
    const int seg0 = bbase[b], seg1 = bbase[b + 1];
    const int len = seg1 - seg0;
    const unsigned* st = staging + seg0;
    for (int i = tid; i < len; i += 256)
        atomicAdd(&scnt[(st[i] >> 17) & (TS - 1)], 1);
    __syncthreads();
    if (tid < TS) sscan[tid] = scnt[tid];
    __syncthreads();
    for (int off = 1; off < TS; off <<= 1) {
        int v = (tid < TS && tid >= off) ? sscan[tid - off] : 0;
        __syncthreads();
        if (tid < TS) sscan[tid] += v;
        __syncthreads();
    }
    const int node0 = b << TSH;
    if (tid < TS) {
        int excl = sscan[tid] - scnt[tid];
        spos[tid] = excl;
        int n = node0 + tid;
        if (n <= N) rowptr[n] = seg0 + excl;
    }
    __syncthreads();
    for (int i = tid; i < len; i += 256) {
        unsigned w = st[i];
        int dl = (w >> 17) & (TS - 1);
        int s = (int)(w & 0x1FFFFu);
        int p = atomicAdd(&scur[dl], 1);
        csr[seg0 + spos[dl] + p] = s;
    }
}

// ---------------- W prep (parallel): Wt (16384) + Wt2 (8192) ----------------
__global__ __launch_bounds__(256) void wprep_kernel(
    const float* __restrict__ W1l, const float* __restrict__ W1r,
    const float* __restrict__ W2l, const float* __restrict__ W2r,
    unsigned short* __restrict__ Wt, unsigned short* __restrict__ Wt2)
{
    const int gid = blockIdx.x * 256 + threadIdx.x;
    if (gid < 16384) {
        int k = gid >> 7;
        int c = gid & 127;
        float v = (c < 64) ? W1l[k * 64 + c] : W1r[k * 64 + (c - 64)];
        Wt[c * 128 + k] = f2b(v);
    } else if (gid < 24576) {
        int idx = gid - 16384;
        int c = idx >> 7;                   // 0..63
        int k = idx & 127;                  // 0..127
        float v = 0.f;
        if (c < NCLS) v = (k < 64) ? W2r[k * NCLS + c] : W2l[(k - 64) * NCLS + c];
        Wt2[c * 128 + k] = f2b(v);
    }
}

// ---------------- layer-1 MFMA GEMM: p1f8 = fp8(x@W1l), qb = bf16(x@W1r + b1) ----------------
__global__ __launch_bounds__(256) void gemm1_kernel(
    const float* __restrict__ x, const unsigned short* __restrict__ Wt,
    const float* __restrict__ b1,
    unsigned char* __restrict__ p1f8, unsigned short* __restrict__ qb, int N)
{
    __shared__ alignas(16) unsigned short sW[128 * 136];
    const int tid = threadIdx.x;
    {
        const int4v* Wg = (const int4v*)Wt;
        #pragma unroll
        for (int i = 0; i < 8; i++) {
            int idx16 = i * 256 + tid;
            int c = idx16 >> 4;
            int k8 = idx16 & 15;
            int4v v = Wg[idx16];
            *(int4v*)&sW[c * 136 + k8 * 8] = v;
        }
    }
    __syncthreads();

    const int w = tid >> 6;
    const int lane = tid & 63;
    const int m = lane & 15;
    const int g = lane >> 4;

    const int node0 = blockIdx.x * 64;
    int arow = node0 + w * 16 + m;
    int arow_c = arow < N ? arow : 0;
    const float* xr = x + (size_t)arow_c * F_IN;

    f32x4 acc[8];
    #pragma unroll
    for (int c = 0; c < 8; c++) acc[c] = (f32x4){0.f, 0.f, 0.f, 0.f};

    #pragma unroll
    for (int ks = 0; ks < 4; ks++) {
        const int k0 = ks * 32 + g * 8;
        f32x4 xa = *(const f32x4*)(xr + k0);
        f32x4 xb = *(const f32x4*)(xr + k0 + 4);
        bf16x8 a;
        a[0] = (short)f2b(xa.x); a[1] = (short)f2b(xa.y);
        a[2] = (short)f2b(xa.z); a[3] = (short)f2b(xa.w);
        a[4] = (short)f2b(xb.x); a[5] = (short)f2b(xb.y);
        a[6] = (short)f2b(xb.z); a[7] = (short)f2b(xb.w);
        #pragma unroll
        for (int ct = 0; ct < 8; ct++) {
            bf16x8 b = *(const bf16x8*)&sW[(ct * 16 + m) * 136 + k0];
            acc[ct] = __builtin_amdgcn_mfma_f32_16x16x32_bf16(a, b, acc[ct], 0, 0, 0);
        }
    }

    float bias[4];
    #pragma unroll
    for (int ct = 4; ct < 8; ct++) bias[ct - 4] = b1[(ct - 4) * 16 + m];

    #pragma unroll
    for (int ct = 0; ct < 8; ct++) {
        const int col = ct * 16 + m;
        #pragma unroll
        for (int r = 0; r < 4; r++) {
            int nd = node0 + w * 16 + g * 4 + r;
            if (nd < N) {
                if (col < 64) {
                    float v = acc[ct][r];
                    int pk = __builtin_amdgcn_cvt_pk_fp8_f32(v, v, 0, false);
                    p1f8[(size_t)nd * HID + col] = (unsigned char)(pk & 0xff);
                } else {
                    qb[(size_t)nd * HID + (col - 64)] = f2b(acc[ct][r] + bias[ct - 4]);
                }
            }
        }
    }
}

// fp8 8-byte chunk -> accumulate into 4 packed-f32 pairs
#define ACC8(A, V)                                            \
    A[0] += __builtin_amdgcn_cvt_pk_f32_fp8((V).x, false);    \
    A[1] += __builtin_amdgcn_cvt_pk_f32_fp8((V).x, true);     \
    A[2] += __builtin_amdgcn_cvt_pk_f32_fp8((V).y, false);    \
    A[3] += __builtin_amdgcn_cvt_pk_f32_fp8((V).y, true);

// ---------------- agg1: h = relu(mean(fp8 p1[nbrs]) + qb); store hb (bf16) + hf8 (fp8) ----------------
// 4 nodes per wave; per node 2 slots x 8 feat-lanes; 4 rows in flight per slot
__global__ __launch_bounds__(256) void agg1_kernel(
    const int* __restrict__ rowptr, const int* __restrict__ csr,
    const unsigned char* __restrict__ p1f8, const unsigned short* __restrict__ qb,
    unsigned short* __restrict__ hb, unsigned char* __restrict__ hf8, int N)
{
    const int wid = (blockIdx.x * 256 + threadIdx.x) >> 6;
    const int lane = threadIdx.x & 63;
    const int nw   = lane >> 4;          // node within wave (0..3)
    const int slot = (lane >> 3) & 1;    // 2 slots per node
    const int fg   = lane & 7;           // 8 feat-lanes, 8 fp8 each
    const int node = wid * 4 + nw;
    int beg = 0, end = 0;
    if (node < N) { beg = rowptr[node]; end = rowptr[node + 1]; }

    f32x2 a0[4], a1[4], a2[4], a3[4];
    #pragma unroll
    for (int q = 0; q < 4; q++) {
        a0[q] = (f32x2){0.f, 0.f}; a1[q] = (f32x2){0.f, 0.f};
        a2[q] = (f32x2){0.f, 0.f}; a3[q] = (f32x2){0.f, 0.f};
    }
    int j = beg + slot;
    for (; j + 6 < end; j += 8) {
        int s0 = csr[j];
        int s1 = csr[j + 2];
        int s2 = csr[j + 4];
        int s3 = csr[j + 6];
        int2v v0 = *(const int2v*)(p1f8 + (size_t)s0 * HID + fg * 8);
        int2v v1 = *(const int2v*)(p1f8 + (size_t)s1 * HID + fg * 8);
        int2v v2 = *(const int2v*)(p1f8 + (size_t)s2 * HID + fg * 8);
        int2v v3 = *(const int2v*)(p1f8 + (size_t)s3 * HID + fg * 8);
        ACC8(a0, v0) ACC8(a1, v1) ACC8(a2, v2) ACC8(a3, v3)
    }
    for (; j < end; j += 2) {
        int s0 = csr[j];
        int2v v0 = *(const int2v*)(p1f8 + (size_t)s0 * HID + fg * 8);
        ACC8(a0, v0)
    }
    float acc[8];
    #pragma unroll
    for (int q = 0; q < 4; q++) {
        acc[2 * q]     = (a0[q].x + a1[q].x) + (a2[q].x + a3[q].x);
        acc[2 * q + 1] = (a0[q].y + a1[q].y) + (a2[q].y + a3[q].y);
    }
    // cross-slot reduce: single step (slot pairs differ by lane bit 3)
    #pragma unroll
    for (int k = 0; k < 8; k++) acc[k] += __shfl_xor(acc[k], 8);

    if (slot == 0 && node < N) {
        float dg = (float)(end - beg);
        dg = dg > 1.f ? dg : 1.f;
        float inv = 1.f / dg;
        bf16x8 q = *(const bf16x8*)(qb + (size_t)node * HID + fg * 8);
        float hv[8];
        bf16x8 ov;
        #pragma unroll
        for (int k = 0; k < 8; k++) {
            float v = acc[k] * inv + b2f((unsigned short)q[k]);
            v = v > 0.f ? v : 0.f;
            hv[k] = v;
            ov[k] = (short)f2b(v);
        }
        *(bf16x8*)(hb + (size_t)node * HID + fg * 8) = ov;
        int w0 = __builtin_amdgcn_cvt_pk_fp8_f32(hv[0], hv[1], 0, false);
        w0     = __builtin_amdgcn_cvt_pk_fp8_f32(hv[2], hv[3], w0, true);
        int w1 = __builtin_amdgcn_cvt_pk_fp8_f32(hv[4], hv[5], 0, false);
        w1     = __builtin_amdgcn_cvt_pk_fp8_f32(hv[6], hv[7], w1, true);
        int2v wv; wv.x = w0; wv.y = w1;
        *(int2v*)(hf8 + (size_t)node * HID + fg * 8) = wv;
    }
}

// ---------------- fused final: agg2 gather (fp8 h) -> LDS, then MFMA + log_softmax ----------------
// block = 64 nodes, 4 waves. Phase 1: each wave gathers 16 nodes (4 rounds of 4-node layout)
// into sagg LDS. Phase 2: MFMA [hb | sagg] @ Wt2, softmax, store.
__global__ __launch_bounds__(256) void final_kernel(
    const int* __restrict__ rowptr, const int* __restrict__ csr,
    const unsigned char* __restrict__ hf8,
    const unsigned short* __restrict__ hb,
    const unsigned short* __restrict__ Wt2, const float* __restrict__ b2,
    float* __restrict__ out, int N)
{
    __shared__ alignas(16) unsigned short sW[64 * 136];    // 17.4 KB
    __shared__ alignas(16) unsigned short sagg[64 * 72];   // 9.2 KB, stride 72 (144B rows)
    const int tid = threadIdx.x;
    const int node0 = blockIdx.x * 64;
    {
        const int4v* Wg = (const int4v*)Wt2;
        #pragma unroll
        for (int i = 0; i < 4; i++) {
            int idx16 = i * 256 + tid;            // 0..1023
            int c = idx16 >> 4;
            int k8 = idx16 & 15;
            int4v v = Wg[idx16];
            *(int4v*)&sW[c * 136 + k8 * 8] = v;
        }
    }
    // zero-init sagg (covers tail nodes >= N)
    {
        int4v z = (int4v){0, 0, 0, 0};
        #pragma unroll
        for (int i = 0; i < 3; i++) {
            int idx16 = i * 256 + tid;            // 0..767 chunks of 8 shorts; 64*72/8 = 576
            if (idx16 < 576) *(int4v*)&sagg[idx16 * 8] = z;
        }
    }
    __syncthreads();

    const int w = tid >> 6;
    const int lane = tid & 63;

    // ---- phase 1: gather agg2 for this block's 64 nodes ----
    {
        const int nw   = lane >> 4;
        const int slot = (lane >> 3) & 1;
        const int fg   = lane & 7;
        #pragma unroll
        for (int rd = 0; rd < 4; rd++) {
            const int nloc = w * 16 + rd * 4 + nw;
            const int node = node0 + nloc;
            int beg = 0, end = 0;
            if (node < N) { beg = rowptr[node]; end = rowptr[node + 1]; }
            f32x2 a0[4], a1[4], a2[4], a3[4];
            #pragma unroll
            for (int q = 0; q < 4; q++) {
                a0[q] = (f32x2){0.f, 0.f}; a1[q] = (f32x2){0.f, 0.f};
                a2[q] = (f32x2){0.f, 0.f}; a3[q] = (f32x2){0.f, 0.f};
            }
            int j = beg + slot;
            for (; j + 6 < end; j += 8) {
                int s0 = csr[j];
                int s1 = csr[j + 2];
                int s2 = csr[j + 4];
                int s3 = csr[j + 6];
                int2v v0 = *(const int2v*)(hf8 + (size_t)s0 * HID + fg * 8);
                int2v v1 = *(const int2v*)(hf8 + (size_t)s1 * HID + fg * 8);
                int2v v2 = *(const int2v*)(hf8 + (size_t)s2 * HID + fg * 8);
                int2v v3 = *(const int2v*)(hf8 + (size_t)s3 * HID + fg * 8);
                ACC8(a0, v0) ACC8(a1, v1) ACC8(a2, v2) ACC8(a3, v3)
            }
            for (; j < end; j += 2) {
                int s0 = csr[j];
                int2v v0 = *(const int2v*)(hf8 + (size_t)s0 * HID + fg * 8);
                ACC8(a0, v0)
            }
            float acc[8];
            #pragma unroll
            for (int q = 0; q < 4; q++) {
                acc[2 * q]     = (a0[q].x + a1[q].x) + (a2[q].x + a3[q].x);
                acc[2 * q + 1] = (a0[q].y + a1[q].y) + (a2[q].y + a3[q].y);
            }
            #pragma unroll
            for (int k = 0; k < 8; k++) acc[k] += __shfl_xor(acc[k], 8);
            if (slot == 0 && node < N) {
                float dg = (float)(end - beg);
                dg = dg > 1.f ? dg : 1.f;
                float inv = 1.f / dg;
                bf16x8 ov;
                #pragma unroll
                for (int k = 0; k < 8; k++) ov[k] = (short)f2b(acc[k] * inv);
                *(bf16x8*)&sagg[nloc * 72 + fg * 8] = ov;
            }
        }
    }
    __syncthreads();

    // ---- phase 2: MFMA + log_softmax ----
    const int m = lane & 15;
    const int g = lane >> 4;
    int arow = node0 + w * 16 + m;
    int arow_c = arow < N ? arow : 0;
    const unsigned short* hr = hb + (size_t)arow_c * HID;
    const unsigned short* sr = &sagg[(w * 16 + m) * 72];

    f32x4 acc[3];
    #pragma unroll
    for (int c = 0; c < 3; c++) acc[c] = (f32x4){0.f, 0.f, 0.f, 0.f};

    #pragma unroll
    for (int ks = 0; ks < 4; ks++) {
        const int k0 = ks * 32 + g * 8;           // never straddles 64
        bf16x8 a = (k0 < 64) ? *(const bf16x8*)(hr + k0)
                             : *(const bf16x8*)(sr + (k0 - 64));
        #pragma unroll
        for (int ct = 0; ct < 3; ct++) {
            bf16x8 b = *(const bf16x8*)&sW[(ct * 16 + m) * 136 + k0];
            acc[ct] = __builtin_amdgcn_mfma_f32_16x16x32_bf16(a, b, acc[ct], 0, 0, 0);
        }
    }

    float bias[3];
    #pragma unroll
    for (int ct = 0; ct < 3; ct++) {
        int col = ct * 16 + m;
        bias[ct] = (col < NCLS) ? b2[col] : 0.f;
    }
    const bool v2 = (m < 8);

    #pragma unroll
    for (int r = 0; r < 4; r++) {
        int nd = node0 + w * 16 + g * 4 + r;
        float l0 = acc[0][r] + bias[0];
        float l1 = acc[1][r] + bias[1];
        float l2 = acc[2][r] + bias[2];
        float mx = fmaxf(l0, l1);
        if (v2) mx = fmaxf(mx, l2);
        mx = fmaxf(mx, __shfl_xor(mx, 1));
        mx = fmaxf(mx, __shfl_xor(mx, 2));
        mx = fmaxf(mx, __shfl_xor(mx, 4));
        mx = fmaxf(mx, __shfl_xor(mx, 8));
        float s = __expf(l0 - mx) + __expf(l1 - mx) + (v2 ? __expf(l2 - mx) : 0.f);
        s += __shfl_xor(s, 1);
        s += __shfl_xor(s, 2);
        s += __shfl_xor(s, 4);
        s += __shfl_xor(s, 8);
        float lse = mx + __logf(s);
        if (nd < N) {
            float* orow = out + (size_t)nd * NCLS;
            orow[m] = l0 - lse;
            orow[16 + m] = l1 - lse;
            if (v2) orow[32 + m] = l2 - lse;
        }
    }
}

extern "C" void kernel_launch(void* const* d_in, const int* in_sizes, int n_in,
                              void* d_out, int out_size, void* d_ws, size_t ws_size,
                              hipStream_t stream) {
    const float* x   = (const float*)d_in[0];
    const int*   ei  = (const int*)d_in[1];
    const float* W1l = (const float*)d_in[2];
    const float* W1r = (const float*)d_in[3];
    const float* b1  = (const float*)d_in[4];
    const float* W2l = (const float*)d_in[5];
    const float* W2r = (const float*)d_in[6];
    const float* b2  = (const float*)d_in[7];

    const int N = in_sizes[0] / F_IN;
    const int E = in_sizes[1] / 2;
    const int* src = ei;
    const int* dst = ei + E;
    const int NB = (N + TS - 1) >> TSH;    // 782 for N=100000

    // ---- workspace layout (int elements) ----
    int* wsi = (int*)d_ws;
    size_t o = 0;
    int* rowptr = wsi + o;  o += (size_t)N + 64;            // N+1
    int* btot   = wsi + o;  o += 1024;
    int* bbase  = wsi + o;  o += 1024;                      // NB+1
    int* ghist  = wsi + o;  o += (size_t)NW * GH;           // [block][tile]
    int* goff   = wsi + o;  o += (size_t)NBMAX * NW;        // [tile][block]
    o = (o + 63) & ~(size_t)63;
    unsigned* staging = (unsigned*)(wsi + o);  o += E;      // tile-grouped packed edges
    int* csr    = wsi + o;  o += E;
    o = (o + 63) & ~(size_t)63;
    unsigned short* Wt  = (unsigned short*)(wsi + o);  o += 8192;            // 128x128 bf16
    unsigned short* Wt2 = (unsigned short*)(wsi + o);  o += 4096;            // 64x128 bf16
    unsigned char*  p1f8 = (unsigned char*)(wsi + o);  o += (size_t)16 * N;  // 64N fp8
    unsigned char*  hf8  = (unsigned char*)(wsi + o);  o += (size_t)16 * N;  // 64N fp8
    unsigned short* hb   = (unsigned short*)(wsi + o); o += (size_t)32 * N;  // 64N bf16
    unsigned short* qb   = (unsigned short*)(wsi + o); o += (size_t)32 * N;  // 64N bf16
    float* out  = (float*)d_out;

    hist_kernel <<<NW, 256, 0, stream>>>(dst, ghist, E, NB);
    btot_kernel <<<NB, 256, 0, stream>>>(ghist, btot);
    bscan_kernel<<<1, 256, 0, stream>>>(btot, bbase, NB);
    boff_kernel <<<NB, 256, 0, stream>>>(ghist, bbase, goff);
    part_kernel <<<NW, 256, 0, stream>>>(src, dst, goff, staging, E, NB);
    build_kernel<<<NB, 256, 0, stream>>>(staging, bbase, rowptr, csr, N);

    wprep_kernel<<<96, 256, 0, stream>>>(W1l, W1r, W2l, W2r, Wt, Wt2);
    gemm1_kernel<<<(N + 63) / 64, 256, 0, stream>>>(x, Wt, b1, p1f8, qb, N);
    agg1_kernel<<<(N + 15) / 16, 256, 0, stream>>>(rowptr, csr, p1f8, qb, hb, hf8, N);
    final_kernel<<<(N + 63) / 64, 256, 0, stream>>>(rowptr, csr, hf8, hb, Wt2, b2, out, N);
}

// Round 18
// 130.938 us; speedup vs baseline: 1.0585x; 1.0585x over previous
//
#include <hip/hip_runtime.h>

#define F_IN 128
#define HID 64
#define NCLS 40

#define TSH 7              // tile shift
#define TS  128            // nodes per dst tile
#define NBMAX 800          // max tiles (N <= 102400)
#define GH 800             // ghist stride
#define NW 256             // writer blocks for hist/part

typedef __attribute__((ext_vector_type(8))) short bf16x8;
typedef __attribute__((ext_vector_type(4))) float f32x4;
typedef __attribute__((ext_vector_type(2))) float f32x2;
typedef __attribute__((ext_vector_type(4))) int int4v;
typedef __attribute__((ext_vector_type(2))) int int2v;

__device__ __forceinline__ unsigned short f2b(float f) {
    union { float f; unsigned int u; } v; v.f = f;
    unsigned int u = v.u + 0x7FFFu + ((v.u >> 16) & 1u);
    return (unsigned short)(u >> 16);
}
__device__ __forceinline__ float b2f(unsigned short b) {
    union { unsigned int u; float f; } v; v.u = ((unsigned int)b) << 16;
    return v.f;
}

// ---------------- K1: per-block histogram over dst tiles (int4 loads) ----------------
__global__ __launch_bounds__(256) void hist_kernel(
    const int* __restrict__ dst, int* __restrict__ ghist, int E, int NB)
{
    __shared__ int h[NBMAX];
    const int tid = threadIdx.x;
    for (int i = tid; i < NBMAX; i += 256) h[i] = 0;
    __syncthreads();
    int chunk = (E + NW - 1) / NW;
    chunk = (chunk + 3) & ~3;
    const int lo = blockIdx.x * chunk;
    const int hi = min(E, lo + chunk);
    for (int e = lo + tid * 4; e + 3 < hi; e += 1024) {
        int4v d4 = *(const int4v*)(dst + e);
        atomicAdd(&h[d4.x >> TSH], 1);
        atomicAdd(&h[d4.y >> TSH], 1);
        atomicAdd(&h[d4.z >> TSH], 1);
        atomicAdd(&h[d4.w >> TSH], 1);
    }
    {
        int tb = hi & ~3;
        if (tb < hi) {
            for (int e = tb + tid; e < hi; e += 256)
                atomicAdd(&h[dst[e] >> TSH], 1);
        }
    }
    __syncthreads();
    for (int bk = tid; bk < NB; bk += 256)
        ghist[blockIdx.x * GH + bk] = h[bk];
}

// ---------------- K2: tile totals ----------------
__global__ __launch_bounds__(256) void btot_kernel(
    const int* __restrict__ ghist, int* __restrict__ btot)
{
    __shared__ int s[256];
    const int bk = blockIdx.x, t = threadIdx.x;
    s[t] = ghist[t * GH + bk];
    __syncthreads();
    for (int off = 128; off > 0; off >>= 1) {
        if (t < off) s[t] += s[t + off];
        __syncthreads();
    }
    if (t == 0) btot[bk] = s[0];
}

// ---------------- K3: parallel exclusive scan of tile totals -> bbase ----------------
__global__ __launch_bounds__(256) void bscan_kernel(
    const int* __restrict__ btot, int* __restrict__ bbase, int NB)
{
    __shared__ int sls[256];
    const int t = threadIdx.x;
    const int base = t * 4;
    int a[4];
    #pragma unroll
    for (int k = 0; k < 4; k++) a[k] = (base + k < NB) ? btot[base + k] : 0;
    a[1] += a[0]; a[2] += a[1]; a[3] += a[2];
    sls[t] = a[3];
    __syncthreads();
    for (int off = 1; off < 256; off <<= 1) {
        int v = (t >= off) ? sls[t - off] : 0;
        __syncthreads();
        sls[t] += v;
        __syncthreads();
    }
    const int prefix = sls[t] - a[3];
    #pragma unroll
    for (int k = 0; k < 4; k++) {
        int excl = prefix + (k > 0 ? a[k - 1] : 0);
        if (base + k < NB) bbase[base + k] = excl;
    }
    if (t == 255) bbase[NB] = sls[255];
}

// ---------------- K4: per-(tile, block) offsets ----------------
__global__ __launch_bounds__(256) void boff_kernel(
    const int* __restrict__ ghist, const int* __restrict__ bbase,
    int* __restrict__ goff)
{
    __shared__ int s[256];
    const int bk = blockIdx.x, t = threadIdx.x;
    const int v = ghist[t * GH + bk];
    s[t] = v;
    __syncthreads();
    for (int off = 1; off < 256; off <<= 1) {
        int u = (t >= off) ? s[t - off] : 0;
        __syncthreads();
        s[t] += u;
        __syncthreads();
    }
    goff[bk * 256 + t] = bbase[bk] + s[t] - v;   // exclusive
}

// ---------------- K5: partition edges into tile-grouped staging (int4 loads) ----------------
__global__ __launch_bounds__(256) void part_kernel(
    const int* __restrict__ src, const int* __restrict__ dst,
    const int* __restrict__ goff, unsigned* __restrict__ staging, int E, int NB)
{
    __shared__ int cur[NBMAX];
    const int tid = threadIdx.x;
    const int blk = blockIdx.x;
    for (int bk = tid; bk < NB; bk += 256) cur[bk] = goff[bk * 256 + blk];
    __syncthreads();
    int chunk = (E + NW - 1) / NW;
    chunk = (chunk + 3) & ~3;
    const int lo = blk * chunk;
    const int hi = min(E, lo + chunk);
    for (int e = lo + tid * 4; e + 3 < hi; e += 1024) {
        int4v d4 = *(const int4v*)(dst + e);
        int4v s4 = *(const int4v*)(src + e);
        int d[4] = {d4.x, d4.y, d4.z, d4.w};
        int s[4] = {s4.x, s4.y, s4.z, s4.w};
        #pragma unroll
        for (int k = 0; k < 4; k++) {
            int bk = d[k] >> TSH;
            int p = atomicAdd(&cur[bk], 1);
            staging[p] = ((unsigned)(d[k] & (TS - 1)) << 17) | (unsigned)s[k];
        }
    }
    {
        int tb = hi & ~3;
        if (tb < hi) {
            for (int e = tb + tid; e < hi; e += 256) {
                int d = dst[e], s = src[e];
                int bk = d >> TSH;
                int p = atomicAdd(&cur[bk], 1);
                staging[p] = ((unsigned)(d & (TS - 1)) << 17) | (unsigned)s;
            }
        }
    }
}

// ---------------- K6: per-tile CSR build; csr stores BYTE offsets (s*64) ----------------
__global__ __launch_bounds__(256) void build_kernel(
    const unsigned* __restrict__ staging, const int* __restrict__ bbase,
    int* __restrict__ rowptr, int* __restrict__ csr, int N)
{
    __shared__ int scnt[TS];
    __shared__ int sscan[TS];
    __shared__ int spos[TS];
    __shared__ int scur[TS];
    const int b = blockIdx.x, tid = threadIdx.x;
    if (tid < TS) { scnt[tid] = 0; scur[tid] = 0; }
    __syncthreads();
    const int seg0 = bbase[b], seg1 = bbase[b + 1];
    const int len = seg1 - seg0;
    const unsigned* st = staging + seg0;
    for (int i = tid; i < len; i += 256)
        atomicAdd(&scnt[(st[i] >> 17) & (TS - 1)], 1);
    __syncthreads();
    if (tid < TS) sscan[tid] = scnt[tid];
    __syncthreads();
    for (int off = 1; off < TS; off <<= 1) {
        int v = (tid < TS && tid >= off) ? sscan[tid - off] : 0;
        __syncthreads();
        if (tid < TS) sscan[tid] += v;
        __syncthreads();
    }
    const int node0 = b << TSH;
    if (tid < TS) {
        int excl = sscan[tid] - scnt[tid];
        spos[tid] = excl;
        int n = node0 + tid;
        if (n <= N) rowptr[n] = seg0 + excl;
    }
    __syncthreads();
    for (int i = tid; i < len; i += 256) {
        unsigned w = st[i];
        int dl = (w >> 17) & (TS - 1);
        int s = (int)(w & 0x1FFFFu);
        int p = atomicAdd(&scur[dl], 1);
        csr[seg0 + spos[dl] + p] = s << 6;     // byte offset into 64B-row buffers
    }
}

// ---------------- W prep (parallel): Wt (16384) + Wt2 (8192) ----------------
__global__ __launch_bounds__(256) void wprep_kernel(
    const float* __restrict__ W1l, const float* __restrict__ W1r,
    const float* __restrict__ W2l, const float* __restrict__ W2r,
    unsigned short* __restrict__ Wt, unsigned short* __restrict__ Wt2)
{
    const int gid = blockIdx.x * 256 + threadIdx.x;
    if (gid < 16384) {
        int k = gid >> 7;
        int c = gid & 127;
        float v = (c < 64) ? W1l[k * 64 + c] : W1r[k * 64 + (c - 64)];
        Wt[c * 128 + k] = f2b(v);
    } else if (gid < 24576) {
        int idx = gid - 16384;
        int c = idx >> 7;
        int k = idx & 127;
        float v = 0.f;
        if (c < NCLS) v = (k < 64) ? W2r[k * NCLS + c] : W2l[(k - 64) * NCLS + c];
        Wt2[c * 128 + k] = f2b(v);
    }
}

// ---------------- layer-1 MFMA GEMM: p1f8 = fp8(x@W1l), qb = bf16(x@W1r + b1) ----------------
__global__ __launch_bounds__(256) void gemm1_kernel(
    const float* __restrict__ x, const unsigned short* __restrict__ Wt,
    const float* __restrict__ b1,
    unsigned char* __restrict__ p1f8, unsigned short* __restrict__ qb, int N)
{
    __shared__ alignas(16) unsigned short sW[128 * 136];
    const int tid = threadIdx.x;
    {
        const int4v* Wg = (const int4v*)Wt;
        #pragma unroll
        for (int i = 0; i < 8; i++) {
            int idx16 = i * 256 + tid;
            int c = idx16 >> 4;
            int k8 = idx16 & 15;
            int4v v = Wg[idx16];
            *(int4v*)&sW[c * 136 + k8 * 8] = v;
        }
    }
    __syncthreads();

    const int w = tid >> 6;
    const int lane = tid & 63;
    const int m = lane & 15;
    const int g = lane >> 4;

    const int node0 = blockIdx.x * 64;
    int arow = node0 + w * 16 + m;
    int arow_c = arow < N ? arow : 0;
    const float* xr = x + (size_t)arow_c * F_IN;

    f32x4 acc[8];
    #pragma unroll
    for (int c = 0; c < 8; c++) acc[c] = (f32x4){0.f, 0.f, 0.f, 0.f};

    #pragma unroll
    for (int ks = 0; ks < 4; ks++) {
        const int k0 = ks * 32 + g * 8;
        f32x4 xa = *(const f32x4*)(xr + k0);
        f32x4 xb = *(const f32x4*)(xr + k0 + 4);
        bf16x8 a;
        a[0] = (short)f2b(xa.x); a[1] = (short)f2b(xa.y);
        a[2] = (short)f2b(xa.z); a[3] = (short)f2b(xa.w);
        a[4] = (short)f2b(xb.x); a[5] = (short)f2b(xb.y);
        a[6] = (short)f2b(xb.z); a[7] = (short)f2b(xb.w);
        #pragma unroll
        for (int ct = 0; ct < 8; ct++) {
            bf16x8 b = *(const bf16x8*)&sW[(ct * 16 + m) * 136 + k0];
            acc[ct] = __builtin_amdgcn_mfma_f32_16x16x32_bf16(a, b, acc[ct], 0, 0, 0);
        }
    }

    float bias[4];
    #pragma unroll
    for (int ct = 4; ct < 8; ct++) bias[ct - 4] = b1[(ct - 4) * 16 + m];

    #pragma unroll
    for (int ct = 0; ct < 8; ct++) {
        const int col = ct * 16 + m;
        #pragma unroll
        for (int r = 0; r < 4; r++) {
            int nd = node0 + w * 16 + g * 4 + r;
            if (nd < N) {
                if (col < 64) {
                    float v = acc[ct][r];
                    int pk = __builtin_amdgcn_cvt_pk_fp8_f32(v, v, 0, false);
                    p1f8[(size_t)nd * HID + col] = (unsigned char)(pk & 0xff);
                } else {
                    qb[(size_t)nd * HID + (col - 64)] = f2b(acc[ct][r] + bias[ct - 4]);
                }
            }
        }
    }
}

// fp8 8-byte chunk -> accumulate into 4 packed-f32 pairs
#define ACC8(A, V)                                            \
    A[0] += __builtin_amdgcn_cvt_pk_f32_fp8((V).x, false);    \
    A[1] += __builtin_amdgcn_cvt_pk_f32_fp8((V).x, true);     \
    A[2] += __builtin_amdgcn_cvt_pk_f32_fp8((V).y, false);    \
    A[3] += __builtin_amdgcn_cvt_pk_f32_fp8((V).y, true);

// ---------------- agg1: h = relu(mean(fp8 p1[nbrs]) + qb); store hb (bf16) + hf8 (fp8) ----------------
// 4 nodes per wave; per node 2 slots x 8 feat-lanes; 4 rows in flight per slot
// csr holds BYTE offsets (s*64)
__global__ __launch_bounds__(256) void agg1_kernel(
    const int* __restrict__ rowptr, const int* __restrict__ csr,
    const unsigned char* __restrict__ p1f8, const unsigned short* __restrict__ qb,
    unsigned short* __restrict__ hb, unsigned char* __restrict__ hf8, int N)
{
    const int wid = (blockIdx.x * 256 + threadIdx.x) >> 6;
    const int lane = threadIdx.x & 63;
    const int nw   = lane >> 4;
    const int slot = (lane >> 3) & 1;
    const int fg   = lane & 7;
    const int node = wid * 4 + nw;
    int beg = 0, end = 0;
    if (node < N) { beg = rowptr[node]; end = rowptr[node + 1]; }
    const unsigned char* pbase = p1f8 + fg * 8;

    f32x2 a0[4], a1[4], a2[4], a3[4];
    #pragma unroll
    for (int q = 0; q < 4; q++) {
        a0[q] = (f32x2){0.f, 0.f}; a1[q] = (f32x2){0.f, 0.f};
        a2[q] = (f32x2){0.f, 0.f}; a3[q] = (f32x2){0.f, 0.f};
    }
    int j = beg + slot;
    for (; j + 6 < end; j += 8) {
        unsigned o0 = (unsigned)csr[j];
        unsigned o1 = (unsigned)csr[j + 2];
        unsigned o2 = (unsigned)csr[j + 4];
        unsigned o3 = (unsigned)csr[j + 6];
        int2v v0 = *(const int2v*)(pbase + o0);
        int2v v1 = *(const int2v*)(pbase + o1);
        int2v v2 = *(const int2v*)(pbase + o2);
        int2v v3 = *(const int2v*)(pbase + o3);
        ACC8(a0, v0) ACC8(a1, v1) ACC8(a2, v2) ACC8(a3, v3)
    }
    for (; j < end; j += 2) {
        unsigned o0 = (unsigned)csr[j];
        int2v v0 = *(const int2v*)(pbase + o0);
        ACC8(a0, v0)
    }
    float acc[8];
    #pragma unroll
    for (int q = 0; q < 4; q++) {
        acc[2 * q]     = (a0[q].x + a1[q].x) + (a2[q].x + a3[q].x);
        acc[2 * q + 1] = (a0[q].y + a1[q].y) + (a2[q].y + a3[q].y);
    }
    #pragma unroll
    for (int k = 0; k < 8; k++) acc[k] += __shfl_xor(acc[k], 8);

    if (slot == 0 && node < N) {
        float dg = (float)(end - beg);
        dg = dg > 1.f ? dg : 1.f;
        float inv = 1.f / dg;
        bf16x8 q = *(const bf16x8*)(qb + (size_t)node * HID + fg * 8);
        float hv[8];
        bf16x8 ov;
        #pragma unroll
        for (int k = 0; k < 8; k++) {
            float v = acc[k] * inv + b2f((unsigned short)q[k]);
            v = v > 0.f ? v : 0.f;
            hv[k] = v;
            ov[k] = (short)f2b(v);
        }
        *(bf16x8*)(hb + (size_t)node * HID + fg * 8) = ov;
        int w0 = __builtin_amdgcn_cvt_pk_fp8_f32(hv[0], hv[1], 0, false);
        w0     = __builtin_amdgcn_cvt_pk_fp8_f32(hv[2], hv[3], w0, true);
        int w1 = __builtin_amdgcn_cvt_pk_fp8_f32(hv[4], hv[5], 0, false);
        w1     = __builtin_amdgcn_cvt_pk_fp8_f32(hv[6], hv[7], w1, true);
        int2v wv; wv.x = w0; wv.y = w1;
        *(int2v*)(hf8 + (size_t)node * HID + fg * 8) = wv;
    }
}

// ---------------- agg2: agghb = bf16(mean(fp8 h[nbrs])), 4 nodes/wave, 4-deep ----------------
__global__ __launch_bounds__(256) void agg2_kernel(
    const int* __restrict__ rowptr, const int* __restrict__ csr,
    const unsigned char* __restrict__ hf8, unsigned short* __restrict__ agghb, int N)
{
    const int wid = (blockIdx.x * 256 + threadIdx.x) >> 6;
    const int lane = threadIdx.x & 63;
    const int nw   = lane >> 4;
    const int slot = (lane >> 3) & 1;
    const int fg   = lane & 7;
    const int node = wid * 4 + nw;
    int beg = 0, end = 0;
    if (node < N) { beg = rowptr[node]; end = rowptr[node + 1]; }
    const unsigned char* pbase = hf8 + fg * 8;

    f32x2 a0[4], a1[4], a2[4], a3[4];
    #pragma unroll
    for (int q = 0; q < 4; q++) {
        a0[q] = (f32x2){0.f, 0.f}; a1[q] = (f32x2){0.f, 0.f};
        a2[q] = (f32x2){0.f, 0.f}; a3[q] = (f32x2){0.f, 0.f};
    }
    int j = beg + slot;
    for (; j + 6 < end; j += 8) {
        unsigned o0 = (unsigned)csr[j];
        unsigned o1 = (unsigned)csr[j + 2];
        unsigned o2 = (unsigned)csr[j + 4];
        unsigned o3 = (unsigned)csr[j + 6];
        int2v v0 = *(const int2v*)(pbase + o0);
        int2v v1 = *(const int2v*)(pbase + o1);
        int2v v2 = *(const int2v*)(pbase + o2);
        int2v v3 = *(const int2v*)(pbase + o3);
        ACC8(a0, v0) ACC8(a1, v1) ACC8(a2, v2) ACC8(a3, v3)
    }
    for (; j < end; j += 2) {
        unsigned o0 = (unsigned)csr[j];
        int2v v0 = *(const int2v*)(pbase + o0);
        ACC8(a0, v0)
    }
    float acc[8];
    #pragma unroll
    for (int q = 0; q < 4; q++) {
        acc[2 * q]     = (a0[q].x + a1[q].x) + (a2[q].x + a3[q].x);
        acc[2 * q + 1] = (a0[q].y + a1[q].y) + (a2[q].y + a3[q].y);
    }
    #pragma unroll
    for (int k = 0; k < 8; k++) acc[k] += __shfl_xor(acc[k], 8);

    if (slot == 0 && node < N) {
        float dg = (float)(end - beg);
        dg = dg > 1.f ? dg : 1.f;
        float inv = 1.f / dg;
        bf16x8 ov;
        #pragma unroll
        for (int k = 0; k < 8; k++) ov[k] = (short)f2b(acc[k] * inv);
        *(bf16x8*)(agghb + (size_t)node * HID + fg * 8) = ov;
    }
}

// ---------------- final MFMA: out = log_softmax([hb|agghb] @ Wt2 + b2) ----------------
__global__ __launch_bounds__(256) void final_kernel(
    const unsigned short* __restrict__ hb, const unsigned short* __restrict__ agghb,
    const unsigned short* __restrict__ Wt2, const float* __restrict__ b2,
    float* __restrict__ out, int N)
{
    __shared__ alignas(16) unsigned short sW[64 * 136];   // 17.4 KB
    const int tid = threadIdx.x;
    {
        const int4v* Wg = (const int4v*)Wt2;
        #pragma unroll
        for (int i = 0; i < 4; i++) {
            int idx16 = i * 256 + tid;
            int c = idx16 >> 4;
            int k8 = idx16 & 15;
            int4v v = Wg[idx16];
            *(int4v*)&sW[c * 136 + k8 * 8] = v;
        }
    }
    __syncthreads();

    const int w = tid >> 6;
    const int lane = tid & 63;
    const int m = lane & 15;
    const int g = lane >> 4;

    const int node0 = blockIdx.x * 64;
    int arow = node0 + w * 16 + m;
    int arow_c = arow < N ? arow : 0;
    const unsigned short* hr = hb + (size_t)arow_c * HID;
    const unsigned short* ar = agghb + (size_t)arow_c * HID;

    f32x4 acc[3];
    #pragma unroll
    for (int c = 0; c < 3; c++) acc[c] = (f32x4){0.f, 0.f, 0.f, 0.f};

    #pragma unroll
    for (int ks = 0; ks < 4; ks++) {
        const int k0 = ks * 32 + g * 8;           // never straddles 64
        bf16x8 a = (k0 < 64) ? *(const bf16x8*)(hr + k0)
                             : *(const bf16x8*)(ar + (k0 - 64));
        #pragma unroll
        for (int ct = 0; ct < 3; ct++) {
            bf16x8 b = *(const bf16x8*)&sW[(ct * 16 + m) * 136 + k0];
            acc[ct] = __builtin_amdgcn_mfma_f32_16x16x32_bf16(a, b, acc[ct], 0, 0, 0);
        }
    }

    float bias[3];
    #pragma unroll
    for (int ct = 0; ct < 3; ct++) {
        int col = ct * 16 + m;
        bias[ct] = (col < NCLS) ? b2[col] : 0.f;
    }
    const bool v2 = (m < 8);

    #pragma unroll
    for (int r = 0; r < 4; r++) {
        int nd = node0 + w * 16 + g * 4 + r;
        float l0 = acc[0][r] + bias[0];
        float l1 = acc[1][r] + bias[1];
        float l2 = acc[2][r] + bias[2];
        float mx = fmaxf(l0, l1);
        if (v2) mx = fmaxf(mx, l2);
        mx = fmaxf(mx, __shfl_xor(mx, 1));
        mx = fmaxf(mx, __shfl_xor(mx, 2));
        mx = fmaxf(mx, __shfl_xor(mx, 4));
        mx = fmaxf(mx, __shfl_xor(mx, 8));
        float s = __expf(l0 - mx) + __expf(l1 - mx) + (v2 ? __expf(l2 - mx) : 0.f);
        s += __shfl_xor(s, 1);
        s += __shfl_xor(s, 2);
        s += __shfl_xor(s, 4);
        s += __shfl_xor(s, 8);
        float lse = mx + __logf(s);
        if (nd < N) {
            float* orow = out + (size_t)nd * NCLS;
            orow[m] = l0 - lse;
            orow[16 + m] = l1 - lse;
            if (v2) orow[32 + m] = l2 - lse;
        }
    }
}

extern "C" void kernel_launch(void* const* d_in, const int* in_sizes, int n_in,
                              void* d_out, int out_size, void* d_ws, size_t ws_size,
                              hipStream_t stream) {
    const float* x   = (const float*)d_in[0];
    const int*   ei  = (const int*)d_in[1];
    const float* W1l = (const float*)d_in[2];
    const float* W1r = (const float*)d_in[3];
    const float* b1  = (const float*)d_in[4];
    const float* W2l = (const float*)d_in[5];
    const float* W2r = (const float*)d_in[6];
    const float* b2  = (const float*)d_in[7];

    const int N = in_sizes[0] / F_IN;
    const int E = in_sizes[1] / 2;
    const int* src = ei;
    const int* dst = ei + E;
    const int NB = (N + TS - 1) >> TSH;    // 782 for N=100000

    // ---- workspace layout (int elements) ----
    int* wsi = (int*)d_ws;
    size_t o = 0;
    int* rowptr = wsi + o;  o += (size_t)N + 64;            // N+1
    int* btot   = wsi + o;  o += 1024;
    int* bbase  = wsi + o;  o += 1024;                      // NB+1
    int* ghist  = wsi + o;  o += (size_t)NW * GH;           // [block][tile]
    int* goff   = wsi + o;  o += (size_t)NBMAX * NW;        // [tile][block]
    o = (o + 63) & ~(size_t)63;
    unsigned* staging = (unsigned*)(wsi + o);  o += E;      // tile-grouped packed edges
    int* csr    = wsi + o;  o += E;
    o = (o + 63) & ~(size_t)63;
    unsigned short* Wt  = (unsigned short*)(wsi + o);  o += 8192;            // 128x128 bf16
    unsigned short* Wt2 = (unsigned short*)(wsi + o);  o += 4096;            // 64x128 bf16
    unsigned char*  p1f8 = (unsigned char*)(wsi + o);  o += (size_t)16 * N;  // 64N fp8
    unsigned char*  hf8  = (unsigned char*)(wsi + o);  o += (size_t)16 * N;  // 64N fp8
    unsigned short* hb   = (unsigned short*)(wsi + o); o += (size_t)32 * N;  // 64N bf16
    unsigned short* qb   = (unsigned short*)(wsi + o); o += (size_t)32 * N;  // 64N bf16
    unsigned short* agghb = qb;     // alias: qb dead after agg1
    float* out  = (float*)d_out;

    hist_kernel <<<NW, 256, 0, stream>>>(dst, ghist, E, NB);
    btot_kernel <<<NB, 256, 0, stream>>>(ghist, btot);
    bscan_kernel<<<1, 256, 0, stream>>>(btot, bbase, NB);
    boff_kernel <<<NB, 256, 0, stream>>>(ghist, bbase, goff);
    part_kernel <<<NW, 256, 0, stream>>>(src, dst, goff, staging, E, NB);
    build_kernel<<<NB, 256, 0, stream>>>(staging, bbase, rowptr, csr, N);

    wprep_kernel<<<96, 256, 0, stream>>>(W1l, W1r, W2l, W2r, Wt, Wt2);
    gemm1_kernel<<<(N + 63) / 64, 256, 0, stream>>>(x, Wt, b1, p1f8, qb, N);
    agg1_kernel<<<(N + 15) / 16, 256, 0, stream>>>(rowptr, csr, p1f8, qb, hb, hf8, N);
    agg2_kernel<<<(N + 15) / 16, 256, 0, stream>>>(rowptr, csr, hf8, agghb, N);
    final_kernel<<<(N + 63) / 64, 256, 0, stream>>>(hb, agghb, Wt2, b2, out, N);
}

// Round 19
// 130.173 us; speedup vs baseline: 1.0647x; 1.0059x over previous
//
#include <hip/hip_runtime.h>

#define F_IN 128
#define HID 64
#define NCLS 40

#define TSH 7              // tile shift
#define TS  128            // nodes per dst tile
#define NBMAX 800          // max tiles (N <= 102400)
#define GH 800             // ghist stride
#define NW 256             // writer blocks for hist/part

typedef __attribute__((ext_vector_type(8))) short bf16x8;
typedef __attribute__((ext_vector_type(4))) float f32x4;
typedef __attribute__((ext_vector_type(2))) float f32x2;
typedef __attribute__((ext_vector_type(4))) int int4v;
typedef __attribute__((ext_vector_type(2))) int int2v;

__device__ __forceinline__ unsigned short f2b(float f) {
    union { float f; unsigned int u; } v; v.f = f;
    unsigned int u = v.u + 0x7FFFu + ((v.u >> 16) & 1u);
    return (unsigned short)(u >> 16);
}
__device__ __forceinline__ float b2f(unsigned short b) {
    union { unsigned int u; float f; } v; v.u = ((unsigned int)b) << 16;
    return v.f;
}

// ---------------- K1: per-block histogram over dst tiles (int4 loads) ----------------
__global__ __launch_bounds__(256) void hist_kernel(
    const int* __restrict__ dst, int* __restrict__ ghist, int E, int NB)
{
    __shared__ int h[NBMAX];
    const int tid = threadIdx.x;
    for (int i = tid; i < NBMAX; i += 256) h[i] = 0;
    __syncthreads();
    int chunk = (E + NW - 1) / NW;
    chunk = (chunk + 3) & ~3;
    const int lo = blockIdx.x * chunk;
    const int hi = min(E, lo + chunk);
    for (int e = lo + tid * 4; e + 3 < hi; e += 1024) {
        int4v d4 = *(const int4v*)(dst + e);
        atomicAdd(&h[d4.x >> TSH], 1);
        atomicAdd(&h[d4.y >> TSH], 1);
        atomicAdd(&h[d4.z >> TSH], 1);
        atomicAdd(&h[d4.w >> TSH], 1);
    }
    {
        int tb = hi & ~3;
        if (tb < hi) {
            for (int e = tb + tid; e < hi; e += 256)
                atomicAdd(&h[dst[e] >> TSH], 1);
        }
    }
    __syncthreads();
    for (int bk = tid; bk < NB; bk += 256)
        ghist[blockIdx.x * GH + bk] = h[bk];
}

// ---------------- K2: tile totals ----------------
__global__ __launch_bounds__(256) void btot_kernel(
    const int* __restrict__ ghist, int* __restrict__ btot)
{
    __shared__ int s[256];
    const int bk = blockIdx.x, t = threadIdx.x;
    s[t] = ghist[t * GH + bk];
    __syncthreads();
    for (int off = 128; off > 0; off >>= 1) {
        if (t < off) s[t] += s[t + off];
        __syncthreads();
    }
    if (t == 0) btot[bk] = s[0];
}

// ---------------- K3 (merged): per-(tile,block) offsets; redundant btot scan; blk0 writes bbase ----------------
__global__ __launch_bounds__(256) void boff_kernel(
    const int* __restrict__ ghist, const int* __restrict__ btot,
    int* __restrict__ bbase, int* __restrict__ goff, int NB)
{
    __shared__ int s[256];
    __shared__ int sexc[NBMAX + 4];
    const int bk = blockIdx.x, t = threadIdx.x;

    // phase A: exclusive scan of btot (redundant per block)
    const int base = t * 4;
    int a[4];
    #pragma unroll
    for (int k = 0; k < 4; k++) a[k] = (base + k < NB) ? btot[base + k] : 0;
    a[1] += a[0]; a[2] += a[1]; a[3] += a[2];
    s[t] = a[3];
    __syncthreads();
    for (int off = 1; off < 256; off <<= 1) {
        int v = (t >= off) ? s[t - off] : 0;
        __syncthreads();
        s[t] += v;
        __syncthreads();
    }
    const int prefix = s[t] - a[3];
    #pragma unroll
    for (int k = 0; k < 4; k++) {
        int excl = prefix + (k > 0 ? a[k - 1] : 0);
        if (base + k < NB) sexc[base + k] = excl;
    }
    if (t == 255) sexc[NB] = s[255];
    __syncthreads();
    if (bk == 0) {
        #pragma unroll
        for (int k = 0; k < 4; k++)
            if (base + k < NB) bbase[base + k] = sexc[base + k];
        if (t == 255) bbase[NB] = sexc[NB];
    }
    const int mybase = sexc[bk];

    // phase B: scan this tile's ghist column across writer blocks
    int v = ghist[t * GH + bk];
    __syncthreads();
    s[t] = v;
    __syncthreads();
    for (int off = 1; off < 256; off <<= 1) {
        int u = (t >= off) ? s[t - off] : 0;
        __syncthreads();
        s[t] += u;
        __syncthreads();
    }
    goff[bk * 256 + t] = mybase + s[t] - v;   // exclusive
}

// ---------------- K5: partition edges into tile-grouped staging (int4 loads) ----------------
__global__ __launch_bounds__(256) void part_kernel(
    const int* __restrict__ src, const int* __restrict__ dst,
    const int* __restrict__ goff, unsigned* __restrict__ staging, int E, int NB)
{
    __shared__ int cur[NBMAX];
    const int tid = threadIdx.x;
    const int blk = blockIdx.x;
    for (int bk = tid; bk < NB; bk += 256) cur[bk] = goff[bk * 256 + blk];
    __syncthreads();
    int chunk = (E + NW - 1) / NW;
    chunk = (chunk + 3) & ~3;
    const int lo = blk * chunk;
    const int hi = min(E, lo + chunk);
    for (int e = lo + tid * 4; e + 3 < hi; e += 1024) {
        int4v d4 = *(const int4v*)(dst + e);
        int4v s4 = *(const int4v*)(src + e);
        int d[4] = {d4.x, d4.y, d4.z, d4.w};
        int s[4] = {s4.x, s4.y, s4.z, s4.w};
        #pragma unroll
        for (int k = 0; k < 4; k++) {
            int bk = d[k] >> TSH;
            int p = atomicAdd(&cur[bk], 1);
            staging[p] = ((unsigned)(d[k] & (TS - 1)) << 17) | (unsigned)s[k];
        }
    }
    {
        int tb = hi & ~3;
        if (tb < hi) {
            for (int e = tb + tid; e < hi; e += 256) {
                int d = dst[e], s = src[e];
                int bk = d >> TSH;
                int p = atomicAdd(&cur[bk], 1);
                staging[p] = ((unsigned)(d & (TS - 1)) << 17) | (unsigned)s;
            }
        }
    }
}

// ---------------- K6: per-tile CSR build; csr stores BYTE offsets (s*64) ----------------
__global__ __launch_bounds__(256) void build_kernel(
    const unsigned* __restrict__ staging, const int* __restrict__ bbase,
    int* __restrict__ rowptr, int* __restrict__ csr, int N)
{
    __shared__ int scnt[TS];
    __shared__ int sscan[TS];
    __shared__ int spos[TS];
    __shared__ int scur[TS];
    const int b = blockIdx.x, tid = threadIdx.x;
    if (tid < TS) { scnt[tid] = 0; scur[tid] = 0; }
    __syncthreads();
    const int seg0 = bbase[b], seg1 = bbase[b + 1];
    const int len = seg1 - seg0;
    const unsigned* st = staging + seg0;
    for (int i = tid; i < len; i += 256)
        atomicAdd(&scnt[(st[i] >> 17) & (TS - 1)], 1);
    __syncthreads();
    if (tid < TS) sscan[tid] = scnt[tid];
    __syncthreads();
    for (int off = 1; off < TS; off <<= 1) {
        int v = (tid < TS && tid >= off) ? sscan[tid - off] : 0;
        __syncthreads();
        if (tid < TS) sscan[tid] += v;
        __syncthreads();
    }
    const int node0 = b << TSH;
    if (tid < TS) {
        int excl = sscan[tid] - scnt[tid];
        spos[tid] = excl;
        int n = node0 + tid;
        if (n <= N) rowptr[n] = seg0 + excl;
    }
    __syncthreads();
    for (int i = tid; i < len; i += 256) {
        unsigned w = st[i];
        int dl = (w >> 17) & (TS - 1);
        int s = (int)(w & 0x1FFFFu);
        int p = atomicAdd(&scur[dl], 1);
        csr[seg0 + spos[dl] + p] = s << 6;     // byte offset into 64B-row buffers
    }
}

// ---------------- W prep (parallel): Wt (16384) + Wt2 (8192) ----------------
__global__ __launch_bounds__(256) void wprep_kernel(
    const float* __restrict__ W1l, const float* __restrict__ W1r,
    const float* __restrict__ W2l, const float* __restrict__ W2r,
    unsigned short* __restrict__ Wt, unsigned short* __restrict__ Wt2)
{
    const int gid = blockIdx.x * 256 + threadIdx.x;
    if (gid < 16384) {
        int k = gid >> 7;
        int c = gid & 127;
        float v = (c < 64) ? W1l[k * 64 + c] : W1r[k * 64 + (c - 64)];
        Wt[c * 128 + k] = f2b(v);
    } else if (gid < 24576) {
        int idx = gid - 16384;
        int c = idx >> 7;
        int k = idx & 127;
        float v = 0.f;
        if (c < NCLS) v = (k < 64) ? W2r[k * NCLS + c] : W2l[(k - 64) * NCLS + c];
        Wt2[c * 128 + k] = f2b(v);
    }
}

// ---------------- layer-1 MFMA GEMM (512 thr, 128 nodes/block) ----------------
__global__ __launch_bounds__(512) void gemm1_kernel(
    const float* __restrict__ x, const unsigned short* __restrict__ Wt,
    const float* __restrict__ b1,
    unsigned char* __restrict__ p1f8, unsigned short* __restrict__ qb, int N)
{
    __shared__ alignas(16) unsigned short sW[128 * 136];
    const int tid = threadIdx.x;
    {
        const int4v* Wg = (const int4v*)Wt;
        #pragma unroll
        for (int i = 0; i < 4; i++) {
            int idx16 = i * 512 + tid;            // 0..2047
            int c = idx16 >> 4;
            int k8 = idx16 & 15;
            int4v v = Wg[idx16];
            *(int4v*)&sW[c * 136 + k8 * 8] = v;
        }
    }
    __syncthreads();

    const int w = tid >> 6;        // wave 0..7
    const int lane = tid & 63;
    const int m = lane & 15;
    const int g = lane >> 4;

    const int node0 = blockIdx.x * 128;
    int arow = node0 + w * 16 + m;
    int arow_c = arow < N ? arow : 0;
    const float* xr = x + (size_t)arow_c * F_IN;

    f32x4 acc[8];
    #pragma unroll
    for (int c = 0; c < 8; c++) acc[c] = (f32x4){0.f, 0.f, 0.f, 0.f};

    #pragma unroll
    for (int ks = 0; ks < 4; ks++) {
        const int k0 = ks * 32 + g * 8;
        f32x4 xa = *(const f32x4*)(xr + k0);
        f32x4 xb = *(const f32x4*)(xr + k0 + 4);
        bf16x8 a;
        a[0] = (short)f2b(xa.x); a[1] = (short)f2b(xa.y);
        a[2] = (short)f2b(xa.z); a[3] = (short)f2b(xa.w);
        a[4] = (short)f2b(xb.x); a[5] = (short)f2b(xb.y);
        a[6] = (short)f2b(xb.z); a[7] = (short)f2b(xb.w);
        #pragma unroll
        for (int ct = 0; ct < 8; ct++) {
            bf16x8 b = *(const bf16x8*)&sW[(ct * 16 + m) * 136 + k0];
            acc[ct] = __builtin_amdgcn_mfma_f32_16x16x32_bf16(a, b, acc[ct], 0, 0, 0);
        }
    }

    float bias[4];
    #pragma unroll
    for (int ct = 4; ct < 8; ct++) bias[ct - 4] = b1[(ct - 4) * 16 + m];

    #pragma unroll
    for (int ct = 0; ct < 8; ct++) {
        const int col = ct * 16 + m;
        #pragma unroll
        for (int r = 0; r < 4; r++) {
            int nd = node0 + w * 16 + g * 4 + r;
            if (nd < N) {
                if (col < 64) {
                    float v = acc[ct][r];
                    int pk = __builtin_amdgcn_cvt_pk_fp8_f32(v, v, 0, false);
                    p1f8[(size_t)nd * HID + col] = (unsigned char)(pk & 0xff);
                } else {
                    qb[(size_t)nd * HID + (col - 64)] = f2b(acc[ct][r] + bias[ct - 4]);
                }
            }
        }
    }
}

// fp8 8-byte chunk -> accumulate into 4 packed-f32 pairs
#define ACC8(A, V)                                            \
    A[0] += __builtin_amdgcn_cvt_pk_f32_fp8((V).x, false);    \
    A[1] += __builtin_amdgcn_cvt_pk_f32_fp8((V).x, true);     \
    A[2] += __builtin_amdgcn_cvt_pk_f32_fp8((V).y, false);    \
    A[3] += __builtin_amdgcn_cvt_pk_f32_fp8((V).y, true);

// ---------------- agg1: h = relu(mean(fp8 p1[nbrs]) + qb); store hb (bf16) + hf8 (fp8) ----------------
__global__ __launch_bounds__(256) void agg1_kernel(
    const int* __restrict__ rowptr, const int* __restrict__ csr,
    const unsigned char* __restrict__ p1f8, const unsigned short* __restrict__ qb,
    unsigned short* __restrict__ hb, unsigned char* __restrict__ hf8, int N)
{
    const int wid = (blockIdx.x * 256 + threadIdx.x) >> 6;
    const int lane = threadIdx.x & 63;
    const int nw   = lane >> 4;
    const int slot = (lane >> 3) & 1;
    const int fg   = lane & 7;
    const int node = wid * 4 + nw;
    int beg = 0, end = 0;
    if (node < N) { beg = rowptr[node]; end = rowptr[node + 1]; }
    const unsigned char* pbase = p1f8 + fg * 8;

    f32x2 a0[4], a1[4], a2[4], a3[4];
    #pragma unroll
    for (int q = 0; q < 4; q++) {
        a0[q] = (f32x2){0.f, 0.f}; a1[q] = (f32x2){0.f, 0.f};
        a2[q] = (f32x2){0.f, 0.f}; a3[q] = (f32x2){0.f, 0.f};
    }
    int j = beg + slot;
    for (; j + 6 < end; j += 8) {
        unsigned o0 = (unsigned)csr[j];
        unsigned o1 = (unsigned)csr[j + 2];
        unsigned o2 = (unsigned)csr[j + 4];
        unsigned o3 = (unsigned)csr[j + 6];
        int2v v0 = *(const int2v*)(pbase + o0);
        int2v v1 = *(const int2v*)(pbase + o1);
        int2v v2 = *(const int2v*)(pbase + o2);
        int2v v3 = *(const int2v*)(pbase + o3);
        ACC8(a0, v0) ACC8(a1, v1) ACC8(a2, v2) ACC8(a3, v3)
    }
    for (; j < end; j += 2) {
        unsigned o0 = (unsigned)csr[j];
        int2v v0 = *(const int2v*)(pbase + o0);
        ACC8(a0, v0)
    }
    float acc[8];
    #pragma unroll
    for (int q = 0; q < 4; q++) {
        acc[2 * q]     = (a0[q].x + a1[q].x) + (a2[q].x + a3[q].x);
        acc[2 * q + 1] = (a0[q].y + a1[q].y) + (a2[q].y + a3[q].y);
    }
    #pragma unroll
    for (int k = 0; k < 8; k++) acc[k] += __shfl_xor(acc[k], 8);

    if (slot == 0 && node < N) {
        float dg = (float)(end - beg);
        dg = dg > 1.f ? dg : 1.f;
        float inv = 1.f / dg;
        bf16x8 q = *(const bf16x8*)(qb + (size_t)node * HID + fg * 8);
        float hv[8];
        bf16x8 ov;
        #pragma unroll
        for (int k = 0; k < 8; k++) {
            float v = acc[k] * inv + b2f((unsigned short)q[k]);
            v = v > 0.f ? v : 0.f;
            hv[k] = v;
            ov[k] = (short)f2b(v);
        }
        *(bf16x8*)(hb + (size_t)node * HID + fg * 8) = ov;
        int w0 = __builtin_amdgcn_cvt_pk_fp8_f32(hv[0], hv[1], 0, false);
        w0     = __builtin_amdgcn_cvt_pk_fp8_f32(hv[2], hv[3], w0, true);
        int w1 = __builtin_amdgcn_cvt_pk_fp8_f32(hv[4], hv[5], 0, false);
        w1     = __builtin_amdgcn_cvt_pk_fp8_f32(hv[6], hv[7], w1, true);
        int2v wv; wv.x = w0; wv.y = w1;
        *(int2v*)(hf8 + (size_t)node * HID + fg * 8) = wv;
    }
}

// ---------------- agg2: agghb = bf16(mean(fp8 h[nbrs])), 4 nodes/wave, 4-deep ----------------
__global__ __launch_bounds__(256) void agg2_kernel(
    const int* __restrict__ rowptr, const int* __restrict__ csr,
    const unsigned char* __restrict__ hf8, unsigned short* __restrict__ agghb, int N)
{
    const int wid = (blockIdx.x * 256 + threadIdx.x) >> 6;
    const int lane = threadIdx.x & 63;
    const int nw   = lane >> 4;
    const int slot = (lane >> 3) & 1;
    const int fg   = lane & 7;
    const int node = wid * 4 + nw;
    int beg = 0, end = 0;
    if (node < N) { beg = rowptr[node]; end = rowptr[node + 1]; }
    const unsigned char* pbase = hf8 + fg * 8;

    f32x2 a0[4], a1[4], a2[4], a3[4];
    #pragma unroll
    for (int q = 0; q < 4; q++) {
        a0[q] = (f32x2){0.f, 0.f}; a1[q] = (f32x2){0.f, 0.f};
        a2[q] = (f32x2){0.f, 0.f}; a3[q] = (f32x2){0.f, 0.f};
    }
    int j = beg + slot;
    for (; j + 6 < end; j += 8) {
        unsigned o0 = (unsigned)csr[j];
        unsigned o1 = (unsigned)csr[j + 2];
        unsigned o2 = (unsigned)csr[j + 4];
        unsigned o3 = (unsigned)csr[j + 6];
        int2v v0 = *(const int2v*)(pbase + o0);
        int2v v1 = *(const int2v*)(pbase + o1);
        int2v v2 = *(const int2v*)(pbase + o2);
        int2v v3 = *(const int2v*)(pbase + o3);
        ACC8(a0, v0) ACC8(a1, v1) ACC8(a2, v2) ACC8(a3, v3)
    }
    for (; j < end; j += 2) {
        unsigned o0 = (unsigned)csr[j];
        int2v v0 = *(const int2v*)(pbase + o0);
        ACC8(a0, v0)
    }
    float acc[8];
    #pragma unroll
    for (int q = 0; q < 4; q++) {
        acc[2 * q]     = (a0[q].x + a1[q].x) + (a2[q].x + a3[q].x);
        acc[2 * q + 1] = (a0[q].y + a1[q].y) + (a2[q].y + a3[q].y);
    }
    #pragma unroll
    for (int k = 0; k < 8; k++) acc[k] += __shfl_xor(acc[k], 8);

    if (slot == 0 && node < N) {
        float dg = (float)(end - beg);
        dg = dg > 1.f ? dg : 1.f;
        float inv = 1.f / dg;
        bf16x8 ov;
        #pragma unroll
        for (int k = 0; k < 8; k++) ov[k] = (short)f2b(acc[k] * inv);
        *(bf16x8*)(agghb + (size_t)node * HID + fg * 8) = ov;
    }
}

// ---------------- final MFMA (512 thr, 128 nodes/block): log_softmax([hb|agghb] @ Wt2 + b2) ----------------
__global__ __launch_bounds__(512) void final_kernel(
    const unsigned short* __restrict__ hb, const unsigned short* __restrict__ agghb,
    const unsigned short* __restrict__ Wt2, const float* __restrict__ b2,
    float* __restrict__ out, int N)
{
    __shared__ alignas(16) unsigned short sW[64 * 136];   // 17.4 KB
    const int tid = threadIdx.x;
    {
        const int4v* Wg = (const int4v*)Wt2;
        #pragma unroll
        for (int i = 0; i < 2; i++) {
            int idx16 = i * 512 + tid;            // 0..1023
            int c = idx16 >> 4;
            int k8 = idx16 & 15;
            int4v v = Wg[idx16];
            *(int4v*)&sW[c * 136 + k8 * 8] = v;
        }
    }
    __syncthreads();

    const int w = tid >> 6;        // 0..7
    const int lane = tid & 63;
    const int m = lane & 15;
    const int g = lane >> 4;

    const int node0 = blockIdx.x * 128;
    int arow = node0 + w * 16 + m;
    int arow_c = arow < N ? arow : 0;
    const unsigned short* hr = hb + (size_t)arow_c * HID;
    const unsigned short* ar = agghb + (size_t)arow_c * HID;

    f32x4 acc[3];
    #pragma unroll
    for (int c = 0; c < 3; c++) acc[c] = (f32x4){0.f, 0.f, 0.f, 0.f};

    #pragma unroll
    for (int ks = 0; ks < 4; ks++) {
        const int k0 = ks * 32 + g * 8;           // never straddles 64
        bf16x8 a = (k0 < 64) ? *(const bf16x8*)(hr + k0)
                             : *(const bf16x8*)(ar + (k0 - 64));
        #pragma unroll
        for (int ct = 0; ct < 3; ct++) {
            bf16x8 b = *(const bf16x8*)&sW[(ct * 16 + m) * 136 + k0];
            acc[ct] = __builtin_amdgcn_mfma_f32_16x16x32_bf16(a, b, acc[ct], 0, 0, 0);
        }
    }

    float bias[3];
    #pragma unroll
    for (int ct = 0; ct < 3; ct++) {
        int col = ct * 16 + m;
        bias[ct] = (col < NCLS) ? b2[col] : 0.f;
    }
    const bool v2 = (m < 8);

    #pragma unroll
    for (int r = 0; r < 4; r++) {
        int nd = node0 + w * 16 + g * 4 + r;
        float l0 = acc[0][r] + bias[0];
        float l1 = acc[1][r] + bias[1];
        float l2 = acc[2][r] + bias[2];
        float mx = fmaxf(l0, l1);
        if (v2) mx = fmaxf(mx, l2);
        mx = fmaxf(mx, __shfl_xor(mx, 1));
        mx = fmaxf(mx, __shfl_xor(mx, 2));
        mx = fmaxf(mx, __shfl_xor(mx, 4));
        mx = fmaxf(mx, __shfl_xor(mx, 8));
        float s = __expf(l0 - mx) + __expf(l1 - mx) + (v2 ? __expf(l2 - mx) : 0.f);
        s += __shfl_xor(s, 1);
        s += __shfl_xor(s, 2);
        s += __shfl_xor(s, 4);
        s += __shfl_xor(s, 8);
        float lse = mx + __logf(s);
        if (nd < N) {
            float* orow = out + (size_t)nd * NCLS;
            orow[m] = l0 - lse;
            orow[16 + m] = l1 - lse;
            if (v2) orow[32 + m] = l2 - lse;
        }
    }
}

extern "C" void kernel_launch(void* const* d_in, const int* in_sizes, int n_in,
                              void* d_out, int out_size, void* d_ws, size_t ws_size,
                              hipStream_t stream) {
    const float* x   = (const float*)d_in[0];
    const int*   ei  = (const int*)d_in[1];
    const float* W1l = (const float*)d_in[2];
    const float* W1r = (const float*)d_in[3];
    const float* b1  = (const float*)d_in[4];
    const float* W2l = (const float*)d_in[5];
    const float* W2r = (const float*)d_in[6];
    const float* b2  = (const float*)d_in[7];

    const int N = in_sizes[0] / F_IN;
    const int E = in_sizes[1] / 2;
    const int* src = ei;
    const int* dst = ei + E;
    const int NB = (N + TS - 1) >> TSH;    // 782 for N=100000

    // ---- workspace layout (int elements) ----
    int* wsi = (int*)d_ws;
    size_t o = 0;
    int* rowptr = wsi + o;  o += (size_t)N + 64;            // N+1
    int* btot   = wsi + o;  o += 1024;
    int* bbase  = wsi + o;  o += 1024;                      // NB+1
    int* ghist  = wsi + o;  o += (size_t)NW * GH;           // [block][tile]
    int* goff   = wsi + o;  o += (size_t)NBMAX * NW;        // [tile][block]
    o = (o + 63) & ~(size_t)63;
    unsigned* staging = (unsigned*)(wsi + o);  o += E;      // tile-grouped packed edges
    int* csr    = wsi + o;  o += E;
    o = (o + 63) & ~(size_t)63;
    unsigned short* Wt  = (unsigned short*)(wsi + o);  o += 8192;            // 128x128 bf16
    unsigned short* Wt2 = (unsigned short*)(wsi + o);  o += 4096;            // 64x128 bf16
    unsigned char*  p1f8 = (unsigned char*)(wsi + o);  o += (size_t)16 * N;  // 64N fp8
    unsigned char*  hf8  = (unsigned char*)(wsi + o);  o += (size_t)16 * N;  // 64N fp8
    unsigned short* hb   = (unsigned short*)(wsi + o); o += (size_t)32 * N;  // 64N bf16
    unsigned short* qb   = (unsigned short*)(wsi + o); o += (size_t)32 * N;  // 64N bf16
    unsigned short* agghb = qb;     // alias: qb dead after agg1
    float* out  = (float*)d_out;

    hist_kernel <<<NW, 256, 0, stream>>>(dst, ghist, E, NB);
    btot_kernel <<<NB, 256, 0, stream>>>(ghist, btot);
    boff_kernel <<<NB, 256, 0, stream>>>(ghist, btot, bbase, goff, NB);
    part_kernel <<<NW, 256, 0, stream>>>(src, dst, goff, staging, E, NB);
    build_kernel<<<NB, 256, 0, stream>>>(staging, bbase, rowptr, csr, N);

    wprep_kernel<<<96, 256, 0, stream>>>(W1l, W1r, W2l, W2r, Wt, Wt2);
    gemm1_kernel<<<(N + 127) / 128, 512, 0, stream>>>(x, Wt, b1, p1f8, qb, N);
    agg1_kernel<<<(N + 15) / 16, 256, 0, stream>>>(rowptr, csr, p1f8, qb, hb, hf8, N);
    agg2_kernel<<<(N + 15) / 16, 256, 0, stream>>>(rowptr, csr, hf8, agghb, N);
    final_kernel<<<(N + 127) / 128, 512, 0, stream>>>(hb, agghb, Wt2, b2, out, N);
}